// Round 1
// baseline (1428.820 us; speedup 1.0000x reference)
//
#include <hip/hip_runtime.h>
#include <cstdint>

#define B_ 16
#define C_ 1024
#define Q_ 128
#define H_ 768
#define OUTSTRIDE (4 * H_)  // 3072

// out[m, n] = sum_k A[m*K+k] * W[n*K+k] + bias[n]   (NT gemm, row-major)
__global__ __launch_bounds__(256) void gemm_nt_bias(
    const float* __restrict__ A, const float* __restrict__ W,
    const float* __restrict__ bias, float* __restrict__ out,
    int M, int K, int out_stride) {
  __shared__ float As[64][17];
  __shared__ float Ws[64][17];
  const int tid = threadIdx.x;
  const int bm = blockIdx.y * 64;
  const int bn = blockIdx.x * 64;
  const int tx = tid & 15, ty = tid >> 4;
  const int lr = tid >> 2;       // 0..63
  const int lc = (tid & 3) * 4;  // 0,4,8,12
  float acc[4][4] = {{0.f}};
  for (int k0 = 0; k0 < K; k0 += 16) {
    float4 av = *reinterpret_cast<const float4*>(A + (size_t)(bm + lr) * K + k0 + lc);
    float4 wv = *reinterpret_cast<const float4*>(W + (size_t)(bn + lr) * K + k0 + lc);
    As[lr][lc] = av.x; As[lr][lc + 1] = av.y; As[lr][lc + 2] = av.z; As[lr][lc + 3] = av.w;
    Ws[lr][lc] = wv.x; Ws[lr][lc + 1] = wv.y; Ws[lr][lc + 2] = wv.z; Ws[lr][lc + 3] = wv.w;
    __syncthreads();
#pragma unroll
    for (int kk = 0; kk < 16; ++kk) {
      float ar[4], wr[4];
#pragma unroll
      for (int i = 0; i < 4; ++i) ar[i] = As[ty * 4 + i][kk];
#pragma unroll
      for (int j = 0; j < 4; ++j) wr[j] = Ws[tx * 4 + j][kk];
#pragma unroll
      for (int i = 0; i < 4; ++i)
#pragma unroll
        for (int j = 0; j < 4; ++j) acc[i][j] += ar[i] * wr[j];
    }
    __syncthreads();
  }
#pragma unroll
  for (int i = 0; i < 4; ++i) {
    int m = bm + ty * 4 + i;
#pragma unroll
    for (int j = 0; j < 4; ++j) {
      int n = bn + tx * 4 + j;
      out[(size_t)m * out_stride + n] = acc[i][j] + bias[n];
    }
  }
}

// One block per (b,c). 128 threads (one per q).
// Computes sim[q], softmax -> alpha, a[p], c[p]=ctx*a, q2c=max_q sim.
__global__ __launch_bounds__(128) void attn_kernel(
    float* __restrict__ out,        // [B*C, 4H]; ctx already in cols [0,H)
    const float* __restrict__ qry,  // [B*Q, H]
    const float* __restrict__ w_att,
    const float* __restrict__ b_att,
    const float* __restrict__ cmask,  // [B*C]
    const float* __restrict__ qmask,  // [B*Q]
    float* __restrict__ q2c)          // [B*C]
{
  __shared__ float ctxr[H_];
  __shared__ float ctxw[H_];
  __shared__ float sh_alpha[Q_];
  __shared__ float red[Q_];
  const int tid = threadIdx.x;
  const int bc = blockIdx.x;
  const int b = bc >> 10;
  float* row = out + (size_t)bc * OUTSTRIDE;
  for (int i = tid; i < H_; i += Q_) {
    float v = row[i];
    ctxr[i] = v;
    ctxw[i] = v * w_att[i];
  }
  __syncthreads();
  const float* qrow = qry + (size_t)(b * Q_ + tid) * H_;
  float s = b_att[0];
  for (int p = 0; p < H_; p += 4) {
    float4 qv = *reinterpret_cast<const float4*>(qrow + p);
    s += ctxw[p] * qv.x + ctxw[p + 1] * qv.y + ctxw[p + 2] * qv.z + ctxw[p + 3] * qv.w;
  }
  // max reduce over 128
  red[tid] = s;
  __syncthreads();
  for (int off = 64; off > 0; off >>= 1) {
    if (tid < off) red[tid] = fmaxf(red[tid], red[tid + off]);
    __syncthreads();
  }
  float m = red[0];
  __syncthreads();
  float e = expf(s - m);
  red[tid] = e;
  __syncthreads();
  for (int off = 64; off > 0; off >>= 1) {
    if (tid < off) red[tid] += red[tid + off];
    __syncthreads();
  }
  float denom = red[0];
  float alpha = e / denom * cmask[bc] * qmask[b * Q_ + tid];
  sh_alpha[tid] = alpha;
  if (tid == 0) q2c[bc] = m;
  __syncthreads();
  const float* qb = qry + (size_t)b * Q_ * H_;
#pragma unroll
  for (int i = 0; i < H_ / Q_; ++i) {  // 6 chunks of 128 columns
    int p = tid + i * Q_;
    float acc = 0.f;
#pragma unroll 4
    for (int q = 0; q < Q_; ++q) acc += sh_alpha[q] * qb[(size_t)q * H_ + p];
    row[H_ + p] = acc;
    row[2 * H_ + p] = ctxr[p] * acc;
  }
}

// 3 blocks per batch (p-chunks of 256). Softmax over q2c[b,:], then
// bvec[b,p] = sum_c beta[c]*ctx[b,c,p].
__global__ __launch_bounds__(256) void beta_kernel(
    const float* __restrict__ out,  // ctx section
    const float* __restrict__ q2c,  // [B*C]
    const float* __restrict__ cmask,
    float* __restrict__ bvec)  // [B,H]
{
  __shared__ float beta[C_];
  __shared__ float red[256];
  const int tid = threadIdx.x;
  const int b = blockIdx.x / 3;
  const int chunk = blockIdx.x % 3;
  float vals[4];
  float lm = -1e30f;
#pragma unroll
  for (int i = 0; i < 4; ++i) {
    float v = q2c[b * C_ + tid * 4 + i];
    vals[i] = v;
    lm = fmaxf(lm, v);
  }
  red[tid] = lm;
  __syncthreads();
  for (int off = 128; off > 0; off >>= 1) {
    if (tid < off) red[tid] = fmaxf(red[tid], red[tid + off]);
    __syncthreads();
  }
  float m = red[0];
  __syncthreads();
  float ls = 0.f;
#pragma unroll
  for (int i = 0; i < 4; ++i) {
    vals[i] = expf(vals[i] - m);
    ls += vals[i];
  }
  red[tid] = ls;
  __syncthreads();
  for (int off = 128; off > 0; off >>= 1) {
    if (tid < off) red[tid] += red[tid + off];
    __syncthreads();
  }
  float denom = red[0];
#pragma unroll
  for (int i = 0; i < 4; ++i)
    beta[tid * 4 + i] = vals[i] / denom * cmask[b * C_ + tid * 4 + i];
  __syncthreads();
  int p = chunk * 256 + tid;
  float acc = 0.f;
  const float* base = out + (size_t)b * C_ * OUTSTRIDE + p;
#pragma unroll 4
  for (int c = 0; c < C_; ++c) acc += beta[c] * base[(size_t)c * OUTSTRIDE];
  bvec[b * H_ + p] = acc;
}

// d = ctx * bvec (broadcast over c)
__global__ __launch_bounds__(256) void d_kernel(float* __restrict__ out,
                                               const float* __restrict__ bvec) {
  size_t idx = (size_t)blockIdx.x * blockDim.x + threadIdx.x;
  if (idx >= (size_t)B_ * C_ * H_) return;
  int p = (int)(idx % H_);
  size_t bc = idx / H_;
  int b = (int)(bc >> 10);
  float* row = out + bc * OUTSTRIDE;
  row[3 * H_ + p] = row[p] * bvec[b * H_ + p];
}

extern "C" void kernel_launch(void* const* d_in, const int* in_sizes, int n_in,
                              void* d_out, int out_size, void* d_ws, size_t ws_size,
                              hipStream_t stream) {
  const float* context = (const float*)d_in[0];
  const float* cmask   = (const float*)d_in[1];
  const float* query   = (const float*)d_in[2];
  const float* qmask   = (const float*)d_in[3];
  const float* Wc      = (const float*)d_in[4];
  const float* bc      = (const float*)d_in[5];
  const float* Wq      = (const float*)d_in[6];
  const float* bq      = (const float*)d_in[7];
  const float* w_att   = (const float*)d_in[8];
  const float* b_att   = (const float*)d_in[9];
  float* out = (float*)d_out;

  float* ws_qry  = (float*)d_ws;                       // B*Q*H = 1,572,864 floats
  float* ws_q2c  = ws_qry + (size_t)B_ * Q_ * H_;      // B*C   = 16,384
  float* ws_bvec = ws_q2c + (size_t)B_ * C_;           // B*H   = 12,288

  // qry = query @ Wq^T + bq  -> ws (row stride H)
  {
    dim3 grid(H_ / 64, (B_ * Q_) / 64);
    gemm_nt_bias<<<grid, 256, 0, stream>>>(query, Wq, bq, ws_qry, B_ * Q_, H_, H_);
  }
  // ctx = context @ Wc^T + bc -> out cols [0,H), row stride 4H
  {
    dim3 grid(H_ / 64, (B_ * C_) / 64);
    gemm_nt_bias<<<grid, 256, 0, stream>>>(context, Wc, bc, out, B_ * C_, H_, OUTSTRIDE);
  }
  // attention per (b,c): a, c, q2c
  attn_kernel<<<B_ * C_, Q_, 0, stream>>>(out, ws_qry, w_att, b_att, cmask, qmask, ws_q2c);
  // beta softmax + bvec
  beta_kernel<<<B_ * 3, 256, 0, stream>>>(out, ws_q2c, cmask, ws_bvec);
  // d = ctx * bvec
  {
    size_t n = (size_t)B_ * C_ * H_;
    d_kernel<<<(int)((n + 255) / 256), 256, 0, stream>>>(out, ws_bvec);
  }
}

// Round 2
// 519.645 us; speedup vs baseline: 2.7496x; 2.7496x over previous
//
#include <hip/hip_runtime.h>
#include <cstdint>

#define B_ 16
#define C_ 1024
#define Q_ 128
#define H_ 768
#define OSTR (4 * H_)  // 3072
#define TC 8           // ctx rows per attn block

typedef __attribute__((ext_vector_type(8))) short bf16x8;
typedef __attribute__((ext_vector_type(4))) float f32x4;
typedef __attribute__((ext_vector_type(4))) int int4v;

__device__ inline unsigned short f2bf(float x) {
  union { float f; unsigned u; } v; v.f = x;
  unsigned r = v.u + 0x7FFFu + ((v.u >> 16) & 1u);
  return (unsigned short)(r >> 16);
}

// 8 floats -> 8 bf16 per thread
__global__ __launch_bounds__(256) void f2bf_kernel(
    const float* __restrict__ src, unsigned short* __restrict__ dst, int n8) {
  int i = blockIdx.x * 256 + threadIdx.x;
  if (i >= n8) return;
  float4 a = ((const float4*)src)[2 * i];
  float4 b = ((const float4*)src)[2 * i + 1];
  unsigned u0 = (unsigned)f2bf(a.x) | ((unsigned)f2bf(a.y) << 16);
  unsigned u1 = (unsigned)f2bf(a.z) | ((unsigned)f2bf(a.w) << 16);
  unsigned u2 = (unsigned)f2bf(b.x) | ((unsigned)f2bf(b.y) << 16);
  unsigned u3 = (unsigned)f2bf(b.z) | ((unsigned)f2bf(b.w) << 16);
  int4v o; o[0] = (int)u0; o[1] = (int)u1; o[2] = (int)u2; o[3] = (int)u3;
  ((int4v*)dst)[i] = o;
}

// out[m,n] = sum_k A[m,k]*W[n,k] + bias[n]; A [M][K] bf16, W [N][K] bf16.
// 128x128 tile, 256 threads = 4 waves, each wave 64x64 via 4x4 x mfma 16x16x32.
__global__ __launch_bounds__(256) void gemm_bf16_nt(
    const unsigned short* __restrict__ A, const unsigned short* __restrict__ W,
    const float* __restrict__ bias, float* __restrict__ out,
    int M, int K, int ostr) {
  __shared__ __align__(16) unsigned short As[128 * 32];
  __shared__ __align__(16) unsigned short Ws[128 * 32];
  const int tid = threadIdx.x;
  const int l = tid & 63;
  const int w = tid >> 6;
  const int bm = blockIdx.y * 128;
  const int bn = blockIdx.x * 128;
  const int wr = (w >> 1) * 64;
  const int wc = (w & 1) * 64;
  const int fr = l & 15;   // frag row (and D col)
  const int fq = l >> 4;   // frag k-group (and D row group)
  const int srow = tid >> 1;            // staging row 0..127
  const int shalf = (tid & 1) * 16;     // staging k half

  f32x4 acc[4][4];
#pragma unroll
  for (int i = 0; i < 4; ++i)
#pragma unroll
    for (int j = 0; j < 4; ++j) { acc[i][j][0] = 0.f; acc[i][j][1] = 0.f; acc[i][j][2] = 0.f; acc[i][j][3] = 0.f; }

  for (int k0 = 0; k0 < K; k0 += 32) {
    const int4v* a_src = (const int4v*)(A + (size_t)(bm + srow) * K + k0 + shalf);
    const int4v* w_src = (const int4v*)(W + (size_t)(bn + srow) * K + k0 + shalf);
    int4v av0 = a_src[0], av1 = a_src[1];
    int4v wv0 = w_src[0], wv1 = w_src[1];
    ((int4v*)(As + srow * 32 + shalf))[0] = av0;
    ((int4v*)(As + srow * 32 + shalf))[1] = av1;
    ((int4v*)(Ws + srow * 32 + shalf))[0] = wv0;
    ((int4v*)(Ws + srow * 32 + shalf))[1] = wv1;
    __syncthreads();
    bf16x8 af[4], wf[4];
#pragma unroll
    for (int i = 0; i < 4; ++i)
      af[i] = *(const bf16x8*)(As + (wr + i * 16 + fr) * 32 + fq * 8);
#pragma unroll
    for (int j = 0; j < 4; ++j)
      wf[j] = *(const bf16x8*)(Ws + (wc + j * 16 + fr) * 32 + fq * 8);
#pragma unroll
    for (int i = 0; i < 4; ++i)
#pragma unroll
      for (int j = 0; j < 4; ++j)
        acc[i][j] = __builtin_amdgcn_mfma_f32_16x16x32_bf16(af[i], wf[j], acc[i][j], 0, 0, 0);
    __syncthreads();
  }
#pragma unroll
  for (int i = 0; i < 4; ++i) {
#pragma unroll
    for (int j = 0; j < 4; ++j) {
      int n = bn + wc + j * 16 + fr;
      float bb = bias[n];
#pragma unroll
      for (int r = 0; r < 4; ++r) {
        int m = bm + wr + i * 16 + fq * 4 + r;
        out[(size_t)m * ostr + n] = acc[i][j][r] + bb;
      }
    }
  }
}

// One block per 8 ctx rows; qry tiled through LDS (transposed).
__global__ __launch_bounds__(256) void attn2_kernel(
    float* __restrict__ out, const float* __restrict__ qry,
    const float* __restrict__ w_att, const float* __restrict__ b_att,
    const float* __restrict__ cmask, const float* __restrict__ qmask,
    float* __restrict__ q2c) {
  __shared__ float qT[64][130];       // [p in tile][q]
  __shared__ float cwS[TC][68];       // ctx*w_att tile
  __shared__ float alphaS[TC][132];   // sim -> alpha
  const int tid = threadIdx.x;
  const int bc0 = blockIdx.x * TC;
  const int b = bc0 >> 10;
  const float* qb = qry + (size_t)b * Q_ * H_;

  const int qi = tid & 127;
  const int rh = tid >> 7;  // 0..1 -> rows rh*4..rh*4+3
  const int lq = tid >> 1;           // load: q row
  const int lp0 = (tid & 1) * 32;    // load: p sub-offset
  float acc[4] = {0.f, 0.f, 0.f, 0.f};

  // ---- sim phase ----
  for (int p0 = 0; p0 < H_; p0 += 64) {
    const float* src = qb + (size_t)lq * H_ + p0 + lp0;
#pragma unroll
    for (int k = 0; k < 32; k += 4) {
      float4 v = *(const float4*)(src + k);
      qT[lp0 + k + 0][lq] = v.x; qT[lp0 + k + 1][lq] = v.y;
      qT[lp0 + k + 2][lq] = v.z; qT[lp0 + k + 3][lq] = v.w;
    }
#pragma unroll
    for (int idx = tid; idx < TC * 64; idx += 256) {
      int r = idx >> 6, p = idx & 63;
      cwS[r][p] = out[(size_t)(bc0 + r) * OSTR + p0 + p] * w_att[p0 + p];
    }
    __syncthreads();
#pragma unroll 4
    for (int p4 = 0; p4 < 16; ++p4) {
      float4 cw0 = *(const float4*)&cwS[rh * 4 + 0][p4 * 4];
      float4 cw1 = *(const float4*)&cwS[rh * 4 + 1][p4 * 4];
      float4 cw2 = *(const float4*)&cwS[rh * 4 + 2][p4 * 4];
      float4 cw3 = *(const float4*)&cwS[rh * 4 + 3][p4 * 4];
      const float* c0 = (const float*)&cw0;
      const float* c1 = (const float*)&cw1;
      const float* c2 = (const float*)&cw2;
      const float* c3 = (const float*)&cw3;
#pragma unroll
      for (int k = 0; k < 4; ++k) {
        float qv = qT[p4 * 4 + k][qi];
        acc[0] += c0[k] * qv;
        acc[1] += c1[k] * qv;
        acc[2] += c2[k] * qv;
        acc[3] += c3[k] * qv;
      }
    }
    __syncthreads();
  }
  // ---- softmax over q (per ctx row) ----
  {
    float batt = b_att[0];
#pragma unroll
    for (int r = 0; r < 4; ++r) alphaS[rh * 4 + r][qi] = acc[r] + batt;
  }
  __syncthreads();
  {
    const int r = tid >> 5;
    const int l32 = tid & 31;
    float4 v = *(const float4*)&alphaS[r][l32 * 4];
    float m = fmaxf(fmaxf(v.x, v.y), fmaxf(v.z, v.w));
#pragma unroll
    for (int mask = 16; mask; mask >>= 1) m = fmaxf(m, __shfl_xor(m, mask));
    float e0 = __expf(v.x - m), e1 = __expf(v.y - m);
    float e2 = __expf(v.z - m), e3 = __expf(v.w - m);
    float s = e0 + e1 + e2 + e3;
#pragma unroll
    for (int mask = 16; mask; mask >>= 1) s += __shfl_xor(s, mask);
    float inv = cmask[bc0 + r] / s;
    int q0 = l32 * 4;
    alphaS[r][q0 + 0] = e0 * inv * qmask[b * Q_ + q0 + 0];
    alphaS[r][q0 + 1] = e1 * inv * qmask[b * Q_ + q0 + 1];
    alphaS[r][q0 + 2] = e2 * inv * qmask[b * Q_ + q0 + 2];
    alphaS[r][q0 + 3] = e3 * inv * qmask[b * Q_ + q0 + 3];
    if (l32 == 0) q2c[bc0 + r] = m;
  }
  __syncthreads();
  // ---- PV phase: a[r][p] = sum_q alpha[r][q]*qry[q][p]; write a and c ----
  const int pp = tid & 63;
  const int rg = tid >> 6;  // rows rg and rg+4
  for (int p0 = 0; p0 < H_; p0 += 64) {
    const float* src = qb + (size_t)lq * H_ + p0 + lp0;
#pragma unroll
    for (int k = 0; k < 32; k += 4) {
      float4 v = *(const float4*)(src + k);
      qT[lp0 + k + 0][lq] = v.x; qT[lp0 + k + 1][lq] = v.y;
      qT[lp0 + k + 2][lq] = v.z; qT[lp0 + k + 3][lq] = v.w;
    }
    __syncthreads();
    float a0 = 0.f, a1 = 0.f;
#pragma unroll 8
    for (int q = 0; q < 128; ++q) {
      int qc = (q + 5 * pp) & 127;  // rotation: conflict-free across lanes
      float qv = qT[pp][qc];
      a0 += alphaS[rg][qc] * qv;
      a1 += alphaS[rg + 4][qc] * qv;
    }
    size_t row0 = (size_t)(bc0 + rg) * OSTR;
    size_t row1 = (size_t)(bc0 + rg + 4) * OSTR;
    float ctx0 = out[row0 + p0 + pp];
    float ctx1 = out[row1 + p0 + pp];
    out[row0 + H_ + p0 + pp] = a0;
    out[row1 + H_ + p0 + pp] = a1;
    out[row0 + 2 * H_ + p0 + pp] = ctx0 * a0;
    out[row1 + 2 * H_ + p0 + pp] = ctx1 * a1;
    __syncthreads();
  }
}

// beta softmax + bvec[b,p] = sum_c beta[c]*ctx[b,c,p]
__global__ __launch_bounds__(256) void beta_kernel(
    const float* __restrict__ out, const float* __restrict__ q2c,
    const float* __restrict__ cmask, float* __restrict__ bvec) {
  __shared__ float beta[C_];
  __shared__ float red[256];
  const int tid = threadIdx.x;
  const int b = blockIdx.x / 3;
  const int chunk = blockIdx.x % 3;
  float vals[4];
  float lm = -1e30f;
#pragma unroll
  for (int i = 0; i < 4; ++i) {
    float v = q2c[b * C_ + tid * 4 + i];
    vals[i] = v;
    lm = fmaxf(lm, v);
  }
  red[tid] = lm;
  __syncthreads();
  for (int off = 128; off > 0; off >>= 1) {
    if (tid < off) red[tid] = fmaxf(red[tid], red[tid + off]);
    __syncthreads();
  }
  float m = red[0];
  __syncthreads();
  float ls = 0.f;
#pragma unroll
  for (int i = 0; i < 4; ++i) { vals[i] = __expf(vals[i] - m); ls += vals[i]; }
  red[tid] = ls;
  __syncthreads();
  for (int off = 128; off > 0; off >>= 1) {
    if (tid < off) red[tid] += red[tid + off];
    __syncthreads();
  }
  float denom = red[0];
#pragma unroll
  for (int i = 0; i < 4; ++i)
    beta[tid * 4 + i] = vals[i] / denom * cmask[b * C_ + tid * 4 + i];
  __syncthreads();
  int p = chunk * 256 + tid;
  float acc = 0.f;
  const float* base = out + (size_t)b * C_ * OSTR + p;
#pragma unroll 4
  for (int c = 0; c < C_; ++c) acc += beta[c] * base[(size_t)c * OSTR];
  bvec[b * H_ + p] = acc;
}

__global__ __launch_bounds__(256) void d_kernel(float* __restrict__ out,
                                               const float* __restrict__ bvec) {
  size_t idx = (size_t)blockIdx.x * 256 + threadIdx.x;
  if (idx >= (size_t)B_ * C_ * H_) return;
  int p = (int)(idx % H_);
  size_t bc = idx / H_;
  int b = (int)(bc >> 10);
  float* row = out + bc * OSTR;
  row[3 * H_ + p] = row[p] * bvec[b * H_ + p];
}

extern "C" void kernel_launch(void* const* d_in, const int* in_sizes, int n_in,
                              void* d_out, int out_size, void* d_ws, size_t ws_size,
                              hipStream_t stream) {
  const float* context = (const float*)d_in[0];
  const float* cmask   = (const float*)d_in[1];
  const float* query   = (const float*)d_in[2];
  const float* qmask   = (const float*)d_in[3];
  const float* Wc      = (const float*)d_in[4];
  const float* bc      = (const float*)d_in[5];
  const float* Wq      = (const float*)d_in[6];
  const float* bq      = (const float*)d_in[7];
  const float* w_att   = (const float*)d_in[8];
  const float* b_att   = (const float*)d_in[9];
  float* out = (float*)d_out;

  float* ws_qry  = (float*)d_ws;                      // B*Q*H fp32
  float* ws_q2c  = ws_qry + (size_t)B_ * Q_ * H_;     // B*C
  float* ws_bvec = ws_q2c + (size_t)B_ * C_;          // B*H
  unsigned short* ws_ctxb = (unsigned short*)(ws_bvec + (size_t)B_ * H_);
  unsigned short* ws_qryb = ws_ctxb + (size_t)B_ * C_ * H_;
  unsigned short* ws_Wcb  = ws_qryb + (size_t)B_ * Q_ * H_;
  unsigned short* ws_Wqb  = ws_Wcb + (size_t)H_ * H_;

  // fp32 -> bf16 conversions
  {
    int n8 = B_ * C_ * H_ / 8;
    f2bf_kernel<<<(n8 + 255) / 256, 256, 0, stream>>>(context, ws_ctxb, n8);
  }
  {
    int n8 = B_ * Q_ * H_ / 8;
    f2bf_kernel<<<(n8 + 255) / 256, 256, 0, stream>>>(query, ws_qryb, n8);
  }
  {
    int n8 = H_ * H_ / 8;
    f2bf_kernel<<<(n8 + 255) / 256, 256, 0, stream>>>(Wc, ws_Wcb, n8);
    f2bf_kernel<<<(n8 + 255) / 256, 256, 0, stream>>>(Wq, ws_Wqb, n8);
  }
  // qry = query @ Wq^T + bq  (fp32 out to ws)
  gemm_bf16_nt<<<dim3(H_ / 128, (B_ * Q_) / 128), 256, 0, stream>>>(
      ws_qryb, ws_Wqb, bq, ws_qry, B_ * Q_, H_, H_);
  // ctx = context @ Wc^T + bc (fp32 out cols [0,H), stride 4H)
  gemm_bf16_nt<<<dim3(H_ / 128, (B_ * C_) / 128), 256, 0, stream>>>(
      ws_ctxb, ws_Wcb, bc, out, B_ * C_, H_, OSTR);
  // attention: a, c, q2c
  attn2_kernel<<<(B_ * C_) / TC, 256, 0, stream>>>(out, ws_qry, w_att, b_att,
                                                   cmask, qmask, ws_q2c);
  // beta softmax + bvec
  beta_kernel<<<B_ * 3, 256, 0, stream>>>(out, ws_q2c, cmask, ws_bvec);
  // d = ctx * bvec
  {
    size_t n = (size_t)B_ * C_ * H_;
    d_kernel<<<(int)((n + 255) / 256), 256, 0, stream>>>(out, ws_bvec);
  }
}

// Round 3
// 177.246 us; speedup vs baseline: 8.0612x; 2.9318x over previous
//
#include <hip/hip_runtime.h>
#include <cstdint>

#define B_ 16
#define C_ 1024
#define Q_ 128
#define H_ 768
#define OSTR (4 * H_)  // 3072

typedef __attribute__((ext_vector_type(8))) short bf16x8;
typedef __attribute__((ext_vector_type(4))) float f32x4;
typedef __attribute__((ext_vector_type(4))) int int4v;

__device__ __forceinline__ unsigned short f2bf(float x) {
  union { float f; unsigned u; } v; v.f = x;
  unsigned r = v.u + 0x7FFFu + ((v.u >> 16) & 1u);
  return (unsigned short)(r >> 16);
}
__device__ __forceinline__ unsigned pk2(float a, float b) {
  return (unsigned)f2bf(a) | ((unsigned)f2bf(b) << 16);
}

// 8 floats -> 8 bf16 per thread
__global__ __launch_bounds__(256) void f2bf_kernel(
    const float* __restrict__ src, unsigned short* __restrict__ dst, int n8) {
  int i = blockIdx.x * 256 + threadIdx.x;
  if (i >= n8) return;
  float4 a = ((const float4*)src)[2 * i];
  float4 b = ((const float4*)src)[2 * i + 1];
  int4v o;
  o[0] = (int)pk2(a.x, a.y); o[1] = (int)pk2(a.z, a.w);
  o[2] = (int)pk2(b.x, b.y); o[3] = (int)pk2(b.z, b.w);
  ((int4v*)dst)[i] = o;
}

// NT gemm: out[m,n] = sum_k A[m,k]*W[n,k] + bias[n]. 128x128 tile, 4 waves.
// MODE 0: fp32 out (stride ostr).  MODE 1: bf16 qryW[m][n]=v*watt[n], bf16 qryT[b][n][q]=v.
template <int MODE>
__global__ __launch_bounds__(256) void gemm_bf16_nt(
    const unsigned short* __restrict__ A, const unsigned short* __restrict__ W,
    const float* __restrict__ bias, float* __restrict__ out32, int ostr,
    unsigned short* __restrict__ ob1, unsigned short* __restrict__ ob2,
    const float* __restrict__ watt, int K) {
  __shared__ __align__(16) unsigned short As[128 * 32];
  __shared__ __align__(16) unsigned short Ws[128 * 32];
  const int tid = threadIdx.x;
  const int l = tid & 63;
  const int w = tid >> 6;
  const int bm = blockIdx.y * 128;
  const int bn = blockIdx.x * 128;
  const int wr = (w >> 1) * 64;
  const int wc = (w & 1) * 64;
  const int fr = l & 15;
  const int fq = l >> 4;
  const int srow = tid >> 1;
  const int shalf = (tid & 1) * 16;

  f32x4 acc[4][4];
#pragma unroll
  for (int i = 0; i < 4; ++i)
#pragma unroll
    for (int j = 0; j < 4; ++j)
#pragma unroll
      for (int e = 0; e < 4; ++e) acc[i][j][e] = 0.f;

  for (int k0 = 0; k0 < K; k0 += 32) {
    const int4v* a_src = (const int4v*)(A + (size_t)(bm + srow) * K + k0 + shalf);
    const int4v* w_src = (const int4v*)(W + (size_t)(bn + srow) * K + k0 + shalf);
    int4v av0 = a_src[0], av1 = a_src[1];
    int4v wv0 = w_src[0], wv1 = w_src[1];
    ((int4v*)(As + srow * 32 + shalf))[0] = av0;
    ((int4v*)(As + srow * 32 + shalf))[1] = av1;
    ((int4v*)(Ws + srow * 32 + shalf))[0] = wv0;
    ((int4v*)(Ws + srow * 32 + shalf))[1] = wv1;
    __syncthreads();
    bf16x8 af[4], wf[4];
#pragma unroll
    for (int i = 0; i < 4; ++i)
      af[i] = *(const bf16x8*)(As + (wr + i * 16 + fr) * 32 + fq * 8);
#pragma unroll
    for (int j = 0; j < 4; ++j)
      wf[j] = *(const bf16x8*)(Ws + (wc + j * 16 + fr) * 32 + fq * 8);
#pragma unroll
    for (int i = 0; i < 4; ++i)
#pragma unroll
      for (int j = 0; j < 4; ++j)
        acc[i][j] = __builtin_amdgcn_mfma_f32_16x16x32_bf16(af[i], wf[j], acc[i][j], 0, 0, 0);
    __syncthreads();
  }
#pragma unroll
  for (int i = 0; i < 4; ++i) {
#pragma unroll
    for (int j = 0; j < 4; ++j) {
      int n = bn + wc + j * 16 + fr;
      float bb = bias[n];
      if constexpr (MODE == 0) {
#pragma unroll
        for (int r = 0; r < 4; ++r) {
          int m = bm + wr + i * 16 + fq * 4 + r;
          out32[(size_t)m * ostr + n] = acc[i][j][r] + bb;
        }
      } else {
        float wv = watt[n];
        ushort4 t4;
#pragma unroll
        for (int r = 0; r < 4; ++r) {
          int m = bm + wr + i * 16 + fq * 4 + r;
          float v = acc[i][j][r] + bb;
          ob1[(size_t)m * H_ + n] = f2bf(v * wv);
          (&t4.x)[r] = f2bf(v);
        }
        int bidx = bm >> 7;
        int q0 = wr + i * 16 + fq * 4;
        *(ushort4*)(ob2 + ((size_t)bidx * H_ + n) * Q_ + q0) = t4;
      }
    }
  }
}

// Fused attention: block = 64 ctx rows, 4 waves, MFMA 16x16x32 bf16.
// sim = bf16(ctx) @ qryW^T ; softmax in-reg ; alpha->LDS(bf16,swz) ; a = alpha @ qryT^T.
__global__ __launch_bounds__(256) void attn3_kernel(
    float* __restrict__ out, const unsigned short* __restrict__ qryW,
    const unsigned short* __restrict__ qryT, const float* __restrict__ b_att,
    const float* __restrict__ cmask, const float* __restrict__ qmask,
    float* __restrict__ q2c) {
  __shared__ __align__(16) unsigned char smem[16384 + 65536];
  unsigned char* r1 = smem + 16384;  // sim bufs: j*24576 (A 8K, B 16K); PV bufs: j*32768
  const int tid = threadIdx.x;
  const int lane = tid & 63;
  const int w = tid >> 6;
  const int fr = lane & 15;
  const int g = lane >> 4;
  const int bc0 = blockIdx.x * 64;
  const int b = bc0 >> 10;
  const int wm = w * 16;

  // staging coords
  const int ar = tid >> 2, ak = (tid & 3) * 16;  // A: ctx fp32, 64 rows x 64 k
  const int br = tid >> 1, bk = (tid & 1) * 4;   // B: qryW bf16, 128 rows x 64 k (c16 base)
  const float* aSrcBase = out + (size_t)(bc0 + ar) * OSTR + ak;
  const unsigned short* bSrcBase = qryW + (size_t)(b * Q_ + br) * H_ + bk * 8;
  const int pr = tid >> 1, pc16 = (tid & 1) * 8;  // PV: qryT bf16, 128 rows x 128 q

  f32x4 acc[8];
#pragma unroll
  for (int nf = 0; nf < 8; ++nf)
#pragma unroll
    for (int e = 0; e < 4; ++e) acc[nf][e] = 0.f;

  float4 a0, a1, a2, a3;
  int4v bv0, bv1, bv2, bv3;
  auto LOAD_AB = [&](int t) {
    const float* s = aSrcBase + t * 64;
    a0 = *(const float4*)(s);      a1 = *(const float4*)(s + 4);
    a2 = *(const float4*)(s + 8);  a3 = *(const float4*)(s + 12);
    const int4v* bs = (const int4v*)(bSrcBase + t * 64);
    bv0 = bs[0]; bv1 = bs[1]; bv2 = bs[2]; bv3 = bs[3];
  };
  auto WRITE_AB = [&](int buf) {
    unsigned char* bA = r1 + buf * 24576;
    unsigned char* bB = bA + 8192;
    int4v w0, w1;
    w0[0] = (int)pk2(a0.x, a0.y); w0[1] = (int)pk2(a0.z, a0.w);
    w0[2] = (int)pk2(a1.x, a1.y); w0[3] = (int)pk2(a1.z, a1.w);
    w1[0] = (int)pk2(a2.x, a2.y); w1[1] = (int)pk2(a2.z, a2.w);
    w1[2] = (int)pk2(a3.x, a3.y); w1[3] = (int)pk2(a3.z, a3.w);
    const int c16a = (tid & 3) * 2;
    *(int4v*)(bA + ar * 128 + ((c16a ^ (ar & 7)) << 4)) = w0;
    *(int4v*)(bA + ar * 128 + (((c16a + 1) ^ (ar & 7)) << 4)) = w1;
    *(int4v*)(bB + br * 128 + (((bk + 0) ^ (br & 7)) << 4)) = bv0;
    *(int4v*)(bB + br * 128 + (((bk + 1) ^ (br & 7)) << 4)) = bv1;
    *(int4v*)(bB + br * 128 + (((bk + 2) ^ (br & 7)) << 4)) = bv2;
    *(int4v*)(bB + br * 128 + (((bk + 3) ^ (br & 7)) << 4)) = bv3;
  };

  LOAD_AB(0);
  WRITE_AB(0);
  __syncthreads();

  // ---- sim: acc[nf] = sum_k ctx[row][k] * qryW[q=nf*16+fr][k] ----
  for (int t = 0; t < 12; ++t) {
    const int cur = t & 1;
    if (t < 11) LOAD_AB(t + 1);
    const unsigned char* bA = r1 + cur * 24576;
    const unsigned char* bB = bA + 8192;
    const int rowa = wm + fr;
#pragma unroll
    for (int kk = 0; kk < 2; ++kk) {
      bf16x8 af = *(const bf16x8*)(bA + rowa * 128 + (((kk * 4 + g) ^ (rowa & 7)) << 4));
#pragma unroll
      for (int nf = 0; nf < 8; ++nf) {
        const int rq = nf * 16 + fr;
        bf16x8 bf = *(const bf16x8*)(bB + rq * 128 + (((kk * 4 + g) ^ (rq & 7)) << 4));
        acc[nf] = __builtin_amdgcn_mfma_f32_16x16x32_bf16(af, bf, acc[nf], 0, 0, 0);
      }
    }
    if (t < 11) WRITE_AB(cur ^ 1);
    __syncthreads();
  }

  int4v pv[8];
  auto PV_LOAD = [&](int ch) {
    const int4v* s = (const int4v*)(qryT + ((size_t)b * H_ + ch * 128 + pr) * Q_ + pc16 * 8);
#pragma unroll
    for (int i = 0; i < 8; ++i) pv[i] = s[i];
  };
  auto PV_WRITE = [&](int buf) {
    unsigned char* bP = r1 + buf * 32768;
#pragma unroll
    for (int i = 0; i < 8; ++i)
      *(int4v*)(bP + pr * 256 + (((pc16 + i) ^ (pr & 7)) << 4)) = pv[i];
  };

  PV_LOAD(0);  // overlap HBM latency with softmax

  // ---- softmax over q, alpha -> LDS (bf16, swizzled), q2c ----
  {
    const float batt = b_att[0];
    float qm[8];
#pragma unroll
    for (int nf = 0; nf < 8; ++nf) qm[nf] = qmask[b * Q_ + nf * 16 + fr];
#pragma unroll
    for (int r = 0; r < 4; ++r) {
      float mx = acc[0][r];
#pragma unroll
      for (int nf = 1; nf < 8; ++nf) mx = fmaxf(mx, acc[nf][r]);
      mx = fmaxf(mx, __shfl_xor(mx, 1));
      mx = fmaxf(mx, __shfl_xor(mx, 2));
      mx = fmaxf(mx, __shfl_xor(mx, 4));
      mx = fmaxf(mx, __shfl_xor(mx, 8));
      float e[8], s = 0.f;
#pragma unroll
      for (int nf = 0; nf < 8; ++nf) { e[nf] = __expf(acc[nf][r] - mx); s += e[nf]; }
      s += __shfl_xor(s, 1); s += __shfl_xor(s, 2);
      s += __shfl_xor(s, 4); s += __shfl_xor(s, 8);
      const int rowl = wm + g * 4 + r;
      if (fr == 0) q2c[bc0 + rowl] = mx + batt;
      const float inv = cmask[bc0 + rowl] / s;
#pragma unroll
      for (int nf = 0; nf < 8; ++nf) {
        float al = e[nf] * inv * qm[nf];
        int byo = rowl * 256 + (nf * 16 + fr) * 2;
        byo ^= (rowl & 7) << 4;
        *(unsigned short*)(smem + byo) = f2bf(al);
      }
    }
  }
  PV_WRITE(0);
  __syncthreads();

  // ---- PV: a[row][p] = sum_q alpha[row][q] * qryT[p][q] ----
  bf16x8 paf[4];
  const int rowa2 = wm + fr;
#pragma unroll
  for (int kk = 0; kk < 4; ++kk)
    paf[kk] = *(const bf16x8*)(smem + rowa2 * 256 + (((kk * 4 + g) ^ (rowa2 & 7)) << 4));

  for (int ch = 0; ch < 6; ++ch) {
    const int cur = ch & 1;
    if (ch < 5) PV_LOAD(ch + 1);
    f32x4 pacc[8];
#pragma unroll
    for (int pn = 0; pn < 8; ++pn)
#pragma unroll
      for (int e = 0; e < 4; ++e) pacc[pn][e] = 0.f;
    const unsigned char* bP = r1 + cur * 32768;
#pragma unroll
    for (int pn = 0; pn < 8; ++pn) {
      const int rp = pn * 16 + fr;
#pragma unroll
      for (int kk = 0; kk < 4; ++kk) {
        bf16x8 bf = *(const bf16x8*)(bP + rp * 256 + (((kk * 4 + g) ^ (rp & 7)) << 4));
        pacc[pn] = __builtin_amdgcn_mfma_f32_16x16x32_bf16(paf[kk], bf, pacc[pn], 0, 0, 0);
      }
    }
    const int p0 = ch * 128;
#pragma unroll
    for (int pn = 0; pn < 8; ++pn) {
      const int p = p0 + pn * 16 + fr;
#pragma unroll
      for (int r = 0; r < 4; ++r) {
        const size_t rowg = (size_t)(bc0 + wm + g * 4 + r) * OSTR;
        float av = pacc[pn][r];
        float cx = out[rowg + p];
        out[rowg + H_ + p] = av;
        out[rowg + 2 * H_ + p] = cx * av;
      }
    }
    if (ch < 5) PV_WRITE(cur ^ 1);
    __syncthreads();
  }
}

// beta softmax over c + bvec[b,p] = sum_c beta[c]*ctx[b,c,p]; grid B*12, 64-p chunks
__global__ __launch_bounds__(256) void beta2_kernel(
    const float* __restrict__ out, const float* __restrict__ q2c,
    const float* __restrict__ cmask, float* __restrict__ bvec) {
  __shared__ float sh[C_];
  __shared__ float red[256];
  const int tid = threadIdx.x;
  const int b = blockIdx.x / 12;
  const int p0 = (blockIdx.x % 12) * 64;
  float v[4];
  float lm = -1e30f;
#pragma unroll
  for (int i = 0; i < 4; ++i) {
    v[i] = q2c[b * C_ + i * 256 + tid];
    lm = fmaxf(lm, v[i]);
  }
  red[tid] = lm;
  __syncthreads();
  for (int off = 128; off > 0; off >>= 1) {
    if (tid < off) red[tid] = fmaxf(red[tid], red[tid + off]);
    __syncthreads();
  }
  const float m = red[0];
  __syncthreads();
  float ls = 0.f;
#pragma unroll
  for (int i = 0; i < 4; ++i) {
    float e = __expf(v[i] - m);
    sh[i * 256 + tid] = e * cmask[b * C_ + i * 256 + tid];
    ls += e;
  }
  red[tid] = ls;
  __syncthreads();
  for (int off = 128; off > 0; off >>= 1) {
    if (tid < off) red[tid] += red[tid + off];
    __syncthreads();
  }
  const float denom = red[0];
  const int pp = tid & 63;
  const int cg = tid >> 6;
  const float* base = out + ((size_t)b * C_ + cg) * OSTR + p0 + pp;
  float acc = 0.f;
#pragma unroll 4
  for (int c = cg; c < C_; c += 4) {
    acc += sh[c] * (*base);
    base += 4 * OSTR;
  }
  __syncthreads();
  red[tid] = acc;
  __syncthreads();
  if (tid < 64) {
    float s = red[tid] + red[tid + 64] + red[tid + 128] + red[tid + 192];
    bvec[b * H_ + p0 + tid] = s / denom;
  }
}

// d = ctx * bvec, float4 vectorized
__global__ __launch_bounds__(256) void d2_kernel(float* __restrict__ out,
                                                const float* __restrict__ bvec) {
  const int i = blockIdx.x * 256 + threadIdx.x;  // B*C*192 exact
  const int row = i / 192;
  const int p4 = i - row * 192;
  const int b = row >> 10;
  float4 cx = *(const float4*)(out + (size_t)row * OSTR + p4 * 4);
  float4 bv = *(const float4*)(bvec + b * H_ + p4 * 4);
  float4 d;
  d.x = cx.x * bv.x; d.y = cx.y * bv.y; d.z = cx.z * bv.z; d.w = cx.w * bv.w;
  *(float4*)(out + (size_t)row * OSTR + 3 * H_ + p4 * 4) = d;
}

extern "C" void kernel_launch(void* const* d_in, const int* in_sizes, int n_in,
                              void* d_out, int out_size, void* d_ws, size_t ws_size,
                              hipStream_t stream) {
  const float* context = (const float*)d_in[0];
  const float* cmask   = (const float*)d_in[1];
  const float* query   = (const float*)d_in[2];
  const float* qmask   = (const float*)d_in[3];
  const float* Wc      = (const float*)d_in[4];
  const float* bc      = (const float*)d_in[5];
  const float* Wq      = (const float*)d_in[6];
  const float* bq      = (const float*)d_in[7];
  const float* w_att   = (const float*)d_in[8];
  const float* b_att   = (const float*)d_in[9];
  float* out = (float*)d_out;

  unsigned short* ws_ctxb = (unsigned short*)d_ws;              // B*C*H
  unsigned short* ws_qin  = ws_ctxb + (size_t)B_ * C_ * H_;     // B*Q*H
  unsigned short* ws_Wcb  = ws_qin + (size_t)B_ * Q_ * H_;      // H*H
  unsigned short* ws_Wqb  = ws_Wcb + (size_t)H_ * H_;           // H*H
  unsigned short* ws_qryW = ws_Wqb + (size_t)H_ * H_;           // B*Q*H
  unsigned short* ws_qryT = ws_qryW + (size_t)B_ * Q_ * H_;     // B*H*Q
  float* ws_q2c  = (float*)(ws_qryT + (size_t)B_ * H_ * Q_);    // B*C
  float* ws_bvec = ws_q2c + (size_t)B_ * C_;                    // B*H

  // fp32 -> bf16
  f2bf_kernel<<<(B_ * C_ * H_ / 8 + 255) / 256, 256, 0, stream>>>(context, ws_ctxb, B_ * C_ * H_ / 8);
  f2bf_kernel<<<(B_ * Q_ * H_ / 8 + 255) / 256, 256, 0, stream>>>(query, ws_qin, B_ * Q_ * H_ / 8);
  f2bf_kernel<<<(H_ * H_ / 8 + 255) / 256, 256, 0, stream>>>(Wc, ws_Wcb, H_ * H_ / 8);
  f2bf_kernel<<<(H_ * H_ / 8 + 255) / 256, 256, 0, stream>>>(Wq, ws_Wqb, H_ * H_ / 8);

  // qry projection -> qryW (w_att folded) + qryT (transposed), both bf16
  gemm_bf16_nt<1><<<dim3(H_ / 128, (B_ * Q_) / 128), 256, 0, stream>>>(
      ws_qin, ws_Wqb, bq, nullptr, 0, ws_qryW, ws_qryT, w_att, H_);
  // ctx projection -> out cols [0,H), fp32, stride 4H
  gemm_bf16_nt<0><<<dim3(H_ / 128, (B_ * C_) / 128), 256, 0, stream>>>(
      ws_ctxb, ws_Wcb, bc, out, OSTR, nullptr, nullptr, nullptr, H_);
  // fused attention: a, c, q2c
  attn3_kernel<<<(B_ * C_) / 64, 256, 0, stream>>>(out, ws_qryW, ws_qryT, b_att,
                                                   cmask, qmask, ws_q2c);
  // beta softmax + bvec
  beta2_kernel<<<B_ * 12, 256, 0, stream>>>(out, ws_q2c, cmask, ws_bvec);
  // d = ctx * bvec
  d2_kernel<<<(B_ * C_ * (H_ / 4)) / 256, 256, 0, stream>>>(out, ws_bvec);
}